// Round 9
// baseline (290.184 us; speedup 1.0000x reference)
//
#include <hip/hip_runtime.h>
#include <hip/hip_bf16.h>
#include <cstdint>

// KANLinear fused as ONE bf16 GEMM, K = 1024*8 (spline basis) + 1024 (silu) = 9216.
//   A[b, 8i+k]   = basis_k(x[b,i]);  A[b, 8192+i] = silu(x[b,i])
//   W[o, 8i+k]   = spline_weight[o,i,k];  W[o, 8192+i] = base_weight[o,i]
// out = A @ W^T  (M=8192, N=1024, K=9216), fp32 in/out, bf16 MFMA internal.
//
// R8: BK=128 via four BK=32 sub-buffers (64 KB LDS). m132's BK=128 regression
// was occupancy-driven (3->2 blocks/CU); our grid caps at 2 blocks/CU anyway,
// so only the benefit remains: barriers 144->72, 64 MFMA/wave per vmcnt drain.
// Prep = R7 best-known form (1 thread/x, dense stride-16 stores).

typedef short s16x8 __attribute__((ext_vector_type(8)));   // 8 bf16 in 4 VGPRs
typedef float f32x4 __attribute__((ext_vector_type(4)));

#define GK 9216
#define GN 1024
#define GI 1024
#define GM 8192

#define BS_BLK 32768   // basis+silu: 8192*1024 threads (1 per x)
#define RP_BLK 4608    // repack   : 1024*1152 threads (8 cols each)

__device__ __forceinline__ void cp16(const __hip_bfloat16* g, __hip_bfloat16* l) {
  __builtin_amdgcn_global_load_lds((const __attribute__((address_space(1))) void*)g,
                                   (__attribute__((address_space(3))) void*)l, 16, 0, 0);
}

__device__ __forceinline__ uint32_t bfbits(float f) {   // RTNE bf16 bits, SSA only
  __hip_bfloat16 h = __float2bfloat16(f);
  unsigned short us;
  __builtin_memcpy(&us, &h, 2);
  return (uint32_t)us;
}

__device__ __forceinline__ void basis4(float xv, int& jj, float& w0, float& w1,
                                       float& w2, float& w3) {
  float t = fminf(1.f, fmaxf(-1.f, xv));
  float us = (t + 1.f) * 2.5f;          // (t - grid[3]) / h, grid[3]=-1, h=0.4
  int j = (int)us;
  if (j > 4) j = 4;                     // t==1.0 edge: matches reference exactly
  float u = us - (float)j;
  float u2 = u * u, u3 = u2 * u;
  float om = 1.f - u;
  jj = j;
  w0 = om * om * om * (1.f / 6.f);
  w1 = (3.f * u3 - 6.f * u2 + 4.f) * (1.f / 6.f);
  w2 = (-3.f * u3 + 3.f * u2 + 3.f * u + 1.f) * (1.f / 6.f);
  w3 = u3 * (1.f / 6.f);
}

// --- ONE dispatch: basis+silu (1 thread/x) + weight repack -----------------
__global__ void kan_prep_all(const float* __restrict__ x,
                             const float* __restrict__ baseW,
                             const float* __restrict__ splineW,
                             __hip_bfloat16* __restrict__ W2,
                             __hip_bfloat16* __restrict__ A) {
  int bid = blockIdx.x;
  if (bid < BS_BLK) {
    int t = bid * 256 + threadIdx.x;        // [0, 8192*1024)
    int b = t >> 10, i = t & 1023;
    float xv = x[t];

    // silu -> A[b, 8192+i], 2 B coalesced store
    float sl = xv / (1.f + __expf(-xv));
    A[(size_t)b * GK + 8192 + i] = __float2bfloat16(sl);

    // basis -> A[b, 8i..8i+7]: funnel-shift packed weights into window jj,
    // one dense 16 B store per lane (stride-16 across the wave)
    int jj; float w0, w1, w2, w3;
    basis4(xv, jj, w0, w1, w2, w3);
    uint64_t W64 = (uint64_t)(bfbits(w0) | (bfbits(w1) << 16)) |
                   ((uint64_t)(bfbits(w2) | (bfbits(w3) << 16)) << 32);
    int sh = jj * 16;                                  // 0,16,32,48,64
    uint64_t lo = (jj < 4) ? (W64 << sh) : 0ull;       // guard UB at sh=64
    uint64_t hi = (jj == 0) ? 0ull : (W64 >> (64 - sh));
    uint4 pk;
    pk.x = (uint32_t)lo;  pk.y = (uint32_t)(lo >> 32);
    pk.z = (uint32_t)hi;  pk.w = (uint32_t)(hi >> 32);
    *(uint4*)(A + (size_t)b * GK + (size_t)i * 8) = pk;
  } else {
    // repack: thread handles 8 cols (32 B fp32 in, 16 B bf16 out)
    int t = (bid - BS_BLK) * 256 + threadIdx.x;   // [0, 1024*1152)
    int o = t / 1152;
    int c = (t - o * 1152) * 8;
    const float* src = (c < 8192) ? (splineW + (size_t)o * 8192 + c)
                                  : (baseW + (size_t)o * GI + (c - 8192));
    float4 v0 = ((const float4*)src)[0];
    float4 v1 = ((const float4*)src)[1];
    uint4 pk;
    pk.x = bfbits(v0.x) | (bfbits(v0.y) << 16);
    pk.y = bfbits(v0.z) | (bfbits(v0.w) << 16);
    pk.z = bfbits(v1.x) | (bfbits(v1.y) << 16);
    pk.w = bfbits(v1.z) | (bfbits(v1.w) << 16);
    *(uint4*)(W2 + (size_t)o * GK + c) = pk;
  }
}

// --- GEMM: 128x128 tile, BK=128 via four BK=32 buffers, XCD-swizzled -------
__global__ __launch_bounds__(256) void kan_gemm(
    const __hip_bfloat16* __restrict__ A,   // (8192, 9216) bf16
    const __hip_bfloat16* __restrict__ B,   // (1024, 9216) bf16
    float* __restrict__ C) {                // (8192, 1024) fp32
  __shared__ __align__(16) __hip_bfloat16 As[4][128 * 32];   // 32 KB
  __shared__ __align__(16) __hip_bfloat16 Bs[4][128 * 32];   // 32 KB
  const int tid = threadIdx.x;
  const int lane = tid & 63;
  const int wave = tid >> 6;
  const int wm = wave >> 1, wn = wave & 1;   // 2x2 waves, 64x64 each

  // XCD swizzle (R3: FETCH 599->147 MB): linear%8 picks a group of 8
  // consecutive rowBands; same-XCD readers of an A k-slice share one L2.
  const int linear = blockIdx.y * 8 + blockIdx.x;
  const int rowBand = (linear & 7) * 8 + ((linear >> 3) & 7);
  const int colBand = linear >> 6;
  const int blockRow = rowBand * 128;
  const int blockCol = colBand * 128;

  const __hip_bfloat16* aPtr = A + (size_t)(blockRow + (tid >> 2)) * GK + (tid & 3) * 8;
  const __hip_bfloat16* bPtr = B + (size_t)(blockCol + (tid >> 2)) * GK + (tid & 3) * 8;

  f32x4 acc[4][4] = {};

  const int q = lane >> 4;       // k-quad
  const int r16 = lane & 15;
  const int aRow = wm * 64 + r16;
  const int bRow = wn * 64 + r16;

  for (int kt = 0; kt < GK / 128; ++kt) {       // 72 iters
#pragma unroll
    for (int s = 0; s < 4; ++s) {               // 4 BK=32 sub-tiles
      __hip_bfloat16* lA = As[s] + wave * 512;  // wave-uniform; HW adds lane*16 B
      __hip_bfloat16* lB = Bs[s] + wave * 512;
      cp16(aPtr + s * 32, lA);                          // rows 0..63
      cp16(aPtr + s * 32 + (size_t)64 * GK, lA + 2048); // rows 64..127
      cp16(bPtr + s * 32, lB);
      cp16(bPtr + s * 32 + (size_t)64 * GK, lB + 2048);
    }
    aPtr += 128; bPtr += 128;
    __syncthreads();   // drains vmcnt(0) -> all 8 tiles visible

#pragma unroll
    for (int s = 0; s < 4; ++s) {
      const s16x8* Af = (const s16x8*)As[s];
      const s16x8* Bf = (const s16x8*)Bs[s];
      s16x8 af[4], bfg[4];
#pragma unroll
      for (int tm = 0; tm < 4; ++tm) af[tm] = Af[(aRow + tm * 16) * 4 + q];
#pragma unroll
      for (int tn = 0; tn < 4; ++tn) bfg[tn] = Bf[(bRow + tn * 16) * 4 + q];
#pragma unroll
      for (int tm = 0; tm < 4; ++tm)
#pragma unroll
        for (int tn = 0; tn < 4; ++tn)
          acc[tm][tn] = __builtin_amdgcn_mfma_f32_16x16x32_bf16(
              af[tm], bfg[tn], acc[tm][tn], 0, 0, 0);
    }
    __syncthreads();   // all waves done reading before next overwrite
  }

  // C/D layout: col = lane&15, row = (lane>>4)*4 + reg  [m89-verified]
  const int cRow0 = blockRow + wm * 64 + q * 4;
  const int cCol0 = blockCol + wn * 64 + r16;
#pragma unroll
  for (int tm = 0; tm < 4; ++tm)
#pragma unroll
    for (int tn = 0; tn < 4; ++tn) {
      int col = cCol0 + tn * 16;
#pragma unroll
      for (int r = 0; r < 4; ++r) {
        int row = cRow0 + tm * 16 + r;
        C[(size_t)row * GN + col] = acc[tm][tn][r];
      }
    }
}

// --- emergency fallback if ws_size is too small ----------------------------
__global__ void kan_naive(const float* __restrict__ x,
                          const float* __restrict__ bw,
                          const float* __restrict__ sw,
                          float* __restrict__ out) {
  int o = blockIdx.x * 256 + threadIdx.x;
  int b = blockIdx.y;
  float acc = 0.f;
  for (int i = 0; i < GI; ++i) {
    float xv = x[(size_t)b * GI + i];
    float sl = xv / (1.f + __expf(-xv));
    acc += sl * bw[(size_t)o * GI + i];
    int jj; float w0, w1, w2, w3;
    basis4(xv, jj, w0, w1, w2, w3);
    const float* swr = sw + ((size_t)o * GI + i) * 8 + jj;
    acc += w0 * swr[0] + w1 * swr[1] + w2 * swr[2] + w3 * swr[3];
  }
  out[(size_t)b * GN + o] = acc;
}

extern "C" void kernel_launch(void* const* d_in, const int* in_sizes, int n_in,
                              void* d_out, int out_size, void* d_ws, size_t ws_size,
                              hipStream_t stream) {
  const float* x  = (const float*)d_in[0];   // (8192, 1024) fp32
  const float* bw = (const float*)d_in[1];   // (1024, 1024) fp32
  const float* sw = (const float*)d_in[2];   // (1024, 1024, 8) fp32
  float* out = (float*)d_out;                // (8192, 1024) fp32

  const size_t wBytes = (size_t)GK * GN * 2;   // 18.9 MB repacked weights
  const size_t aBytes = (size_t)GM * GK * 2;   // 151 MB activations
  if (ws_size < wBytes + aBytes) {
    kan_naive<<<dim3(GN / 256, GM), 256, 0, stream>>>(x, bw, sw, out);
    return;
  }

  __hip_bfloat16* W2 = (__hip_bfloat16*)d_ws;
  __hip_bfloat16* Abuf = W2 + (size_t)GK * GN;   // 16B-aligned

  kan_prep_all<<<BS_BLK + RP_BLK, 256, 0, stream>>>(x, bw, sw, W2, Abuf);
  kan_gemm<<<dim3(GN / 128, GM / 128), 256, 0, stream>>>(Abuf, W2, out);
}

// Round 10
// 287.143 us; speedup vs baseline: 1.0106x; 1.0106x over previous
//
#include <hip/hip_runtime.h>
#include <hip/hip_bf16.h>
#include <cstdint>

// KANLinear fused as ONE bf16 GEMM, K = 1024*8 (spline basis) + 1024 (silu) = 9216.
//   A[b, 8i+k]   = basis_k(x[b,i]);  A[b, 8192+i] = silu(x[b,i])
//   W[o, 8i+k]   = spline_weight[o,i,k];  W[o, 8192+i] = base_weight[o,i]
// out = A @ W^T  (M=8192, N=1024, K=9216), fp32 in/out, bf16 MFMA internal.
//
// R9: 512-thread blocks (8 waves of 64x32) on the same 128x128/BK=64 tiles.
// Same traffic, same LDS; doubles waves/CU 8->16 to de-align the
// stage->drain->compute serialization across more independent streams.
// (R8 showed barrier COUNT is not binding; this tests overlap width.)

typedef short s16x8 __attribute__((ext_vector_type(8)));   // 8 bf16 in 4 VGPRs
typedef float f32x4 __attribute__((ext_vector_type(4)));

#define GK 9216
#define GN 1024
#define GI 1024
#define GM 8192

#define BS_BLK 32768   // basis+silu: 8192*1024 threads (1 per x)
#define RP_BLK 4608    // repack   : 1024*1152 threads (8 cols each)

__device__ __forceinline__ void cp16(const __hip_bfloat16* g, __hip_bfloat16* l) {
  __builtin_amdgcn_global_load_lds((const __attribute__((address_space(1))) void*)g,
                                   (__attribute__((address_space(3))) void*)l, 16, 0, 0);
}

__device__ __forceinline__ uint32_t bfbits(float f) {   // RTNE bf16 bits, SSA only
  __hip_bfloat16 h = __float2bfloat16(f);
  unsigned short us;
  __builtin_memcpy(&us, &h, 2);
  return (uint32_t)us;
}

__device__ __forceinline__ void basis4(float xv, int& jj, float& w0, float& w1,
                                       float& w2, float& w3) {
  float t = fminf(1.f, fmaxf(-1.f, xv));
  float us = (t + 1.f) * 2.5f;          // (t - grid[3]) / h, grid[3]=-1, h=0.4
  int j = (int)us;
  if (j > 4) j = 4;                     // t==1.0 edge: matches reference exactly
  float u = us - (float)j;
  float u2 = u * u, u3 = u2 * u;
  float om = 1.f - u;
  jj = j;
  w0 = om * om * om * (1.f / 6.f);
  w1 = (3.f * u3 - 6.f * u2 + 4.f) * (1.f / 6.f);
  w2 = (-3.f * u3 + 3.f * u2 + 3.f * u + 1.f) * (1.f / 6.f);
  w3 = u3 * (1.f / 6.f);
}

// --- ONE dispatch: basis+silu (1 thread/x) + weight repack -----------------
__global__ void kan_prep_all(const float* __restrict__ x,
                             const float* __restrict__ baseW,
                             const float* __restrict__ splineW,
                             __hip_bfloat16* __restrict__ W2,
                             __hip_bfloat16* __restrict__ A) {
  int bid = blockIdx.x;
  if (bid < BS_BLK) {
    int t = bid * 256 + threadIdx.x;        // [0, 8192*1024)
    int b = t >> 10, i = t & 1023;
    float xv = x[t];

    // silu -> A[b, 8192+i], 2 B coalesced store
    float sl = xv / (1.f + __expf(-xv));
    A[(size_t)b * GK + 8192 + i] = __float2bfloat16(sl);

    // basis -> A[b, 8i..8i+7]: funnel-shift packed weights into window jj,
    // one dense 16 B store per lane (stride-16 across the wave)
    int jj; float w0, w1, w2, w3;
    basis4(xv, jj, w0, w1, w2, w3);
    uint64_t W64 = (uint64_t)(bfbits(w0) | (bfbits(w1) << 16)) |
                   ((uint64_t)(bfbits(w2) | (bfbits(w3) << 16)) << 32);
    int sh = jj * 16;                                  // 0,16,32,48,64
    uint64_t lo = (jj < 4) ? (W64 << sh) : 0ull;       // guard UB at sh=64
    uint64_t hi = (jj == 0) ? 0ull : (W64 >> (64 - sh));
    uint4 pk;
    pk.x = (uint32_t)lo;  pk.y = (uint32_t)(lo >> 32);
    pk.z = (uint32_t)hi;  pk.w = (uint32_t)(hi >> 32);
    *(uint4*)(A + (size_t)b * GK + (size_t)i * 8) = pk;
  } else {
    // repack: thread handles 8 cols (32 B fp32 in, 16 B bf16 out)
    int t = (bid - BS_BLK) * 256 + threadIdx.x;   // [0, 1024*1152)
    int o = t / 1152;
    int c = (t - o * 1152) * 8;
    const float* src = (c < 8192) ? (splineW + (size_t)o * 8192 + c)
                                  : (baseW + (size_t)o * GI + (c - 8192));
    float4 v0 = ((const float4*)src)[0];
    float4 v1 = ((const float4*)src)[1];
    uint4 pk;
    pk.x = bfbits(v0.x) | (bfbits(v0.y) << 16);
    pk.y = bfbits(v0.z) | (bfbits(v0.w) << 16);
    pk.z = bfbits(v1.x) | (bfbits(v1.y) << 16);
    pk.w = bfbits(v1.z) | (bfbits(v1.w) << 16);
    *(uint4*)(W2 + (size_t)o * GK + c) = pk;
  }
}

// --- GEMM: 512 threads, 128x128 tile, BK=64 dual BK=32 bufs, XCD-swizzled --
__global__ __launch_bounds__(512) void kan_gemm(
    const __hip_bfloat16* __restrict__ A,   // (8192, 9216) bf16
    const __hip_bfloat16* __restrict__ B,   // (1024, 9216) bf16
    float* __restrict__ C) {                // (8192, 1024) fp32
  __shared__ __align__(16) __hip_bfloat16 As[2][128 * 32];   // 16 KB
  __shared__ __align__(16) __hip_bfloat16 Bs[2][128 * 32];   // 16 KB
  const int tid = threadIdx.x;
  const int lane = tid & 63;
  const int wave = tid >> 6;                 // 0..7
  const int wm = wave >> 2, wn = wave & 3;   // 2x4 waves, 64x32 each

  // XCD swizzle (R3: FETCH 599->147 MB): linear%8 picks a group of 8
  // consecutive rowBands; same-XCD readers of an A k-slice share one L2.
  const int linear = blockIdx.y * 8 + blockIdx.x;
  const int rowBand = (linear & 7) * 8 + ((linear >> 3) & 7);
  const int colBand = linear >> 6;
  const int blockRow = rowBand * 128;
  const int blockCol = colBand * 128;

  // staging: 512 lanes x 16 B = one full 128x32 tile per cp16
  const __hip_bfloat16* aPtr = A + (size_t)(blockRow + (tid >> 2)) * GK + (tid & 3) * 8;
  const __hip_bfloat16* bPtr = B + (size_t)(blockCol + (tid >> 2)) * GK + (tid & 3) * 8;
  __hip_bfloat16* ldsA0 = As[0] + wave * 512;   // wave-uniform; HW adds lane*16 B
  __hip_bfloat16* ldsA1 = As[1] + wave * 512;
  __hip_bfloat16* ldsB0 = Bs[0] + wave * 512;
  __hip_bfloat16* ldsB1 = Bs[1] + wave * 512;

  f32x4 acc[4][2] = {};

  const int q = lane >> 4;       // k-quad
  const int r16 = lane & 15;
  const int aRow = wm * 64 + r16;
  const int bRow = wn * 32 + r16;

  for (int kt = 0; kt < GK / 64; ++kt) {        // 144 iters
    cp16(aPtr, ldsA0);                          // k 0..31, all 128 rows
    cp16(aPtr + 32, ldsA1);                     // k 32..63
    cp16(bPtr, ldsB0);
    cp16(bPtr + 32, ldsB1);
    aPtr += 64; bPtr += 64;
    __syncthreads();   // drains vmcnt(0) -> all 4 tiles visible

#pragma unroll
    for (int s = 0; s < 2; ++s) {
      const s16x8* Af = (const s16x8*)As[s];
      const s16x8* Bf = (const s16x8*)Bs[s];
      s16x8 af[4], bfg[2];
#pragma unroll
      for (int tm = 0; tm < 4; ++tm) af[tm] = Af[(aRow + tm * 16) * 4 + q];
#pragma unroll
      for (int tn = 0; tn < 2; ++tn) bfg[tn] = Bf[(bRow + tn * 16) * 4 + q];
#pragma unroll
      for (int tm = 0; tm < 4; ++tm)
#pragma unroll
        for (int tn = 0; tn < 2; ++tn)
          acc[tm][tn] = __builtin_amdgcn_mfma_f32_16x16x32_bf16(
              af[tm], bfg[tn], acc[tm][tn], 0, 0, 0);
    }
    __syncthreads();   // all waves done reading before next overwrite
  }

  // C/D layout: col = lane&15, row = (lane>>4)*4 + reg  [m89-verified]
  const int cRow0 = blockRow + wm * 64 + q * 4;
  const int cCol0 = blockCol + wn * 32 + r16;
#pragma unroll
  for (int tm = 0; tm < 4; ++tm)
#pragma unroll
    for (int tn = 0; tn < 2; ++tn) {
      int col = cCol0 + tn * 16;
#pragma unroll
      for (int r = 0; r < 4; ++r) {
        int row = cRow0 + tm * 16 + r;
        C[(size_t)row * GN + col] = acc[tm][tn][r];
      }
    }
}

// --- emergency fallback if ws_size is too small ----------------------------
__global__ void kan_naive(const float* __restrict__ x,
                          const float* __restrict__ bw,
                          const float* __restrict__ sw,
                          float* __restrict__ out) {
  int o = blockIdx.x * 256 + threadIdx.x;
  int b = blockIdx.y;
  float acc = 0.f;
  for (int i = 0; i < GI; ++i) {
    float xv = x[(size_t)b * GI + i];
    float sl = xv / (1.f + __expf(-xv));
    acc += sl * bw[(size_t)o * GI + i];
    int jj; float w0, w1, w2, w3;
    basis4(xv, jj, w0, w1, w2, w3);
    const float* swr = sw + ((size_t)o * GI + i) * 8 + jj;
    acc += w0 * swr[0] + w1 * swr[1] + w2 * swr[2] + w3 * swr[3];
  }
  out[(size_t)b * GN + o] = acc;
}

extern "C" void kernel_launch(void* const* d_in, const int* in_sizes, int n_in,
                              void* d_out, int out_size, void* d_ws, size_t ws_size,
                              hipStream_t stream) {
  const float* x  = (const float*)d_in[0];   // (8192, 1024) fp32
  const float* bw = (const float*)d_in[1];   // (1024, 1024) fp32
  const float* sw = (const float*)d_in[2];   // (1024, 1024, 8) fp32
  float* out = (float*)d_out;                // (8192, 1024) fp32

  const size_t wBytes = (size_t)GK * GN * 2;   // 18.9 MB repacked weights
  const size_t aBytes = (size_t)GM * GK * 2;   // 151 MB activations
  if (ws_size < wBytes + aBytes) {
    kan_naive<<<dim3(GN / 256, GM), 256, 0, stream>>>(x, bw, sw, out);
    return;
  }

  __hip_bfloat16* W2 = (__hip_bfloat16*)d_ws;
  __hip_bfloat16* Abuf = W2 + (size_t)GK * GN;   // 16B-aligned

  kan_prep_all<<<BS_BLK + RP_BLK, 256, 0, stream>>>(x, bw, sw, W2, Abuf);
  kan_gemm<<<dim3(GN / 128, GM / 128), 512, 0, stream>>>(Abuf, W2, out);
}